// Round 5
// baseline (675.416 us; speedup 1.0000x reference)
//
#include <hip/hip_runtime.h>
#include <hip/hip_bf16.h>
#include <math.h>

#define GRAPHS 128
#define SCAN_B 256
#define BM 128
#define BN 128
#define BK 64
#define PCH 128   // nodes per pooling block

typedef __attribute__((ext_vector_type(8))) short bfrag8;   // 8 bf16 (4 VGPRs)
typedef __attribute__((ext_vector_type(4))) float f32x4;

__device__ inline unsigned short f2b(float f) {
    unsigned int u = __float_as_uint(f);
    unsigned int r = (u + 0x7fffu + ((u >> 16) & 1u)) >> 16;  // RNE
    return (unsigned short)r;
}
__device__ inline float b2f(unsigned short u) {
    return __uint_as_float(((unsigned int)u) << 16);
}
__device__ inline void unpack8(float* v, uint4 u) {
    v[0] = b2f(u.x & 0xffffu); v[1] = b2f(u.x >> 16);
    v[2] = b2f(u.y & 0xffffu); v[3] = b2f(u.y >> 16);
    v[4] = b2f(u.z & 0xffffu); v[5] = b2f(u.z >> 16);
    v[6] = b2f(u.w & 0xffffu); v[7] = b2f(u.w >> 16);
}

__device__ inline void gload16(const void* g, void* l) {
    typedef unsigned int __attribute__((address_space(1))) gu32;
    typedef unsigned int __attribute__((address_space(3))) su32;
    __builtin_amdgcn_global_load_lds((const gu32*)g, (su32*)l, 16, 0, 0);
}

// ---------------- CSR build ----------------

__global__ void k_count(const int* __restrict__ dst, int* __restrict__ cnt, int E) {
    int i = blockIdx.x * blockDim.x + threadIdx.x;
    if (i < E) atomicAdd(&cnt[dst[i]], 1);
}

__global__ void k_scan1(const int* __restrict__ cnt, int* __restrict__ excl,
                        int* __restrict__ bsum, int n) {
    __shared__ int sh[SCAN_B];
    int t = threadIdx.x;
    int i = blockIdx.x * SCAN_B + t;
    int v = (i < n) ? cnt[i] : 0;
    sh[t] = v;
    __syncthreads();
    for (int off = 1; off < SCAN_B; off <<= 1) {
        int x = (t >= off) ? sh[t - off] : 0;
        __syncthreads();
        sh[t] += x;
        __syncthreads();
    }
    if (i < n) excl[i] = sh[t] - v;
    if (t == SCAN_B - 1) bsum[blockIdx.x] = sh[t];
}

__global__ void k_scan2(int* __restrict__ bsum, int nb) {
    __shared__ int sh[SCAN_B];
    int t = threadIdx.x;
    int v = (t < nb) ? bsum[t] : 0;
    sh[t] = v;
    __syncthreads();
    for (int off = 1; off < SCAN_B; off <<= 1) {
        int x = (t >= off) ? sh[t - off] : 0;
        __syncthreads();
        sh[t] += x;
        __syncthreads();
    }
    if (t < nb) bsum[t] = sh[t] - v;
}

__global__ void k_scan3(int* __restrict__ rowstart, const int* __restrict__ bsum,
                        const int* __restrict__ cnt, float* __restrict__ dinv,
                        int* __restrict__ cursor, int n, int E) {
    int i = blockIdx.x * SCAN_B + threadIdx.x;
    if (i < n) {
        rowstart[i] += bsum[blockIdx.x];
        cursor[i] = 0;
        dinv[i] = rsqrtf((float)cnt[i] + 1.0f);  // +1 self loop
    }
    if (i == 0) rowstart[n] = E;
}

__global__ void k_scatter_csr(const int* __restrict__ src, const int* __restrict__ dst,
                              const float* __restrict__ dinv, const int* __restrict__ rowstart,
                              int* __restrict__ cursor, int2* __restrict__ csr, int E) {
    int e = blockIdx.x * blockDim.x + threadIdx.x;
    if (e >= E) return;
    int s = src[e], d = dst[e];
    int pos = rowstart[d] + atomicAdd(&cursor[d], 1);
    int2 c;
    c.x = s;
    c.y = __float_as_int(dinv[s] * dinv[d]);
    csr[pos] = c;
}

// ---------------- weight transpose + bf16 cast: WT[n][k] = bf16(W[k][n]) ----------------

__global__ void k_wt(const float* __restrict__ W, unsigned short* __restrict__ WT,
                     int K, int N) {
    int idx = blockIdx.x * 256 + threadIdx.x;
    if (idx >= K * N) return;
    int k = idx / N, n2 = idx - k * N;
    WT[(size_t)n2 * K + k] = f2b(W[idx]);
}

// ---------------- x -> bf16 (padded rows zeroed) ----------------

__global__ void k_x2b(const float* __restrict__ x, unsigned short* __restrict__ xb,
                      int n, int mpad) {
    int idx = blockIdx.x * 256 + threadIdx.x;   // one float4 / thread
    if (idx >= mpad * 32) return;               // 128/4 quads per row
    int row = idx >> 5;
    float4 v = {0.f, 0.f, 0.f, 0.f};
    if (row < n) v = ((const float4*)x)[idx];
    ushort4 o;
    o.x = f2b(v.x); o.y = f2b(v.y); o.z = f2b(v.z); o.w = f2b(v.w);
    ((ushort4*)xb)[idx] = o;
}

// ---------------- per-row LN stats: st[row] = (mu, rsigma) ----------------

template <int F>
__global__ void k_stats(const unsigned short* __restrict__ z, float2* __restrict__ st,
                        int mpad) {
    constexpr int V = F / 64;   // 4 (F=256) or 8 (F=512)
    int row = blockIdx.x * 4 + (threadIdx.x >> 6);
    int lane = threadIdx.x & 63;
    const unsigned short* p = z + (size_t)row * F + lane * V;
    float s = 0.f, q = 0.f;
    if constexpr (V == 8) {
        uint4 u = *(const uint4*)p;
        float v[8]; unpack8(v, u);
#pragma unroll
        for (int k = 0; k < 8; ++k) { s += v[k]; q += v[k] * v[k]; }
    } else {
        uint2 u = *(const uint2*)p;
        float v0 = b2f(u.x & 0xffffu), v1 = b2f(u.x >> 16);
        float v2 = b2f(u.y & 0xffffu), v3 = b2f(u.y >> 16);
        s = v0 + v1 + v2 + v3;
        q = v0 * v0 + v1 * v1 + v2 * v2 + v3 * v3;
    }
#pragma unroll
    for (int m = 1; m < 64; m <<= 1) {
        s += __shfl_xor(s, m);
        q += __shfl_xor(q, m);
    }
    if (lane == 0) {
        float mu = s * (1.0f / F);
        float var = q * (1.0f / F) - mu * mu;
        float2 o; o.x = mu; o.y = rsqrtf(var + 1e-5f);
        st[row] = o;
    }
}

// ---------------- wave-cooperative, feature-sliced aggregation ----------------
// One node per wave, 64-col slice per block (slice = blockIdx % NSL -> XCD-pinned).
// 8 edges in parallel (lane>>3) x 8 feature-chunks (lane&7). Optional fused
// LN(+LeakyReLU) of the gathered source rows using per-row stats.

template <int F, bool LN, bool LRELU>
__global__ __launch_bounds__(256) void k_aggw(
    const unsigned short* __restrict__ z, unsigned short* __restrict__ agg,
    const int* __restrict__ rowstart, const int2* __restrict__ csr,
    const float* __restrict__ dinv, const float2* __restrict__ st,
    const float* __restrict__ g, const float* __restrict__ be, int n, int mpad) {
    constexpr int NSL = F / 64;
    const int slice = (int)(blockIdx.x % NSL);
    const int chunk = (int)(blockIdx.x / NSL);
    const int tid = threadIdx.x;
    const int node = chunk * 4 + (tid >> 6);
    const int lane = tid & 63;
    const int e8 = lane >> 3;        // edge sub-slot 0..7
    const int fi = lane & 7;         // feature chunk 0..7 within slice
    const int fo = slice * 64 + fi * 8;
    if (node >= mpad) return;
    unsigned short* outp = agg + (size_t)node * F + fo;
    if (node >= n) {
        if (e8 == 0) { uint4 zz = {0u, 0u, 0u, 0u}; *(uint4*)outp = zz; }
        return;
    }

    float gk[8], bek[8];
    if (LN) {
#pragma unroll
        for (int k = 0; k < 8; ++k) { gk[k] = g[fo + k]; bek[k] = be[fo + k]; }
    }
    const unsigned short* zf = z + fo;
    float a[8] = {};

    int b = rowstart[node], e = rowstart[node + 1];
    for (int j = b + e8; j < e; j += 8) {
        int2 c = csr[j];
        float w = __int_as_float(c.y);
        uint4 u = *(const uint4*)(zf + (size_t)c.x * F);
        float v[8]; unpack8(v, u);
        if (LN) {
            float2 s2 = st[c.x];
#pragma unroll
            for (int k = 0; k < 8; ++k) {
                float y = (v[k] - s2.x) * s2.y * gk[k] + bek[k];
                if (LRELU) y = fmaxf(y, 0.f) + 0.01f * fminf(y, 0.f);
                a[k] += y * w;
            }
        } else {
#pragma unroll
            for (int k = 0; k < 8; ++k) a[k] += v[k] * w;
        }
    }
    // reduce the 8 edge slots (all lanes end with the full sum)
#pragma unroll
    for (int m = 8; m < 64; m <<= 1)
#pragma unroll
        for (int k = 0; k < 8; ++k) a[k] += __shfl_xor(a[k], m);

    if (e8 == 0) {
        float di = dinv[node];
        float w0 = di * di;   // self loop
        uint4 u = *(const uint4*)(zf + (size_t)node * F);
        float v[8]; unpack8(v, u);
        if (LN) {
            float2 s2 = st[node];
#pragma unroll
            for (int k = 0; k < 8; ++k) {
                float y = (v[k] - s2.x) * s2.y * gk[k] + bek[k];
                if (LRELU) y = fmaxf(y, 0.f) + 0.01f * fminf(y, 0.f);
                a[k] += y * w0;
            }
        } else {
#pragma unroll
            for (int k = 0; k < 8; ++k) a[k] += v[k] * w0;
        }
        uint4 o;
        o.x = (unsigned)f2b(a[0]) | ((unsigned)f2b(a[1]) << 16);
        o.y = (unsigned)f2b(a[2]) | ((unsigned)f2b(a[3]) << 16);
        o.z = (unsigned)f2b(a[4]) | ((unsigned)f2b(a[5]) << 16);
        o.w = (unsigned)f2b(a[6]) | ((unsigned)f2b(a[7]) << 16);
        *(uint4*)outp = o;
    }
}

// ---------------- bf16 MFMA GEMM: Z[Mpad,N] = A[Mpad,K] @ BT[N,K]^T + bias (bf16 out) ----

__global__ __launch_bounds__(256) void k_gemm_bf16(
    const unsigned short* __restrict__ A, const unsigned short* __restrict__ BT,
    const float* __restrict__ bias, unsigned short* __restrict__ C, int K, int N) {
    __shared__ __align__(16) char sA[BM * BK * 2];
    __shared__ __align__(16) char sB[BN * BK * 2];

    const int tid = threadIdx.x;
    const int lane = tid & 63;
    const int wave = tid >> 6;
    const int wr = wave >> 1, wc = wave & 1;
    const size_t row0 = (size_t)blockIdx.x * BM;
    const size_t col0 = (size_t)blockIdx.y * BN;

    const unsigned short* srcA[4];
    const unsigned short* srcB[4];
    char* dstA[4];
    char* dstB[4];
#pragma unroll
    for (int c = 0; c < 4; ++c) {
        int idx = c * 256 + tid;
        int row = idx >> 3;
        int cbl = ((idx & 7) << 4) ^ ((row & 7) << 4);
        srcA[c] = A + (row0 + row) * K + (cbl >> 1);
        srcB[c] = BT + (col0 + row) * K + (cbl >> 1);
        dstA[c] = sA + idx * 16;
        dstB[c] = sB + idx * 16;
    }

    const int fr = lane & 15;
    const int fg = lane >> 4;
    const int fsw = (lane & 7) << 4;
    int offA[4][2], offB[4][2];
#pragma unroll
    for (int t = 0; t < 4; ++t)
#pragma unroll
        for (int kk = 0; kk < 2; ++kk) {
            offA[t][kk] = (wr * 64 + t * 16 + fr) * (BK * 2) + ((kk * 64 + fg * 16) ^ fsw);
            offB[t][kk] = (wc * 64 + t * 16 + fr) * (BK * 2) + ((kk * 64 + fg * 16) ^ fsw);
        }

    f32x4 acc[4][4] = {};

    for (int k0 = 0; k0 < K; k0 += BK) {
#pragma unroll
        for (int c = 0; c < 4; ++c) gload16(srcA[c] + k0, dstA[c]);
#pragma unroll
        for (int c = 0; c < 4; ++c) gload16(srcB[c] + k0, dstB[c]);
        __syncthreads();
#pragma unroll
        for (int kk = 0; kk < 2; ++kk) {
            bfrag8 av[4], bv[4];
#pragma unroll
            for (int t = 0; t < 4; ++t) av[t] = *(const bfrag8*)(sA + offA[t][kk]);
#pragma unroll
            for (int t = 0; t < 4; ++t) bv[t] = *(const bfrag8*)(sB + offB[t][kk]);
#pragma unroll
            for (int i = 0; i < 4; ++i)
#pragma unroll
                for (int j = 0; j < 4; ++j)
                    acc[i][j] = __builtin_amdgcn_mfma_f32_16x16x32_bf16(av[i], bv[j],
                                                                        acc[i][j], 0, 0, 0);
        }
        __syncthreads();
    }

#pragma unroll
    for (int i = 0; i < 4; ++i) {
#pragma unroll
        for (int j = 0; j < 4; ++j) {
            size_t r = row0 + wr * 64 + i * 16 + fg * 4;
            size_t cc = col0 + wc * 64 + j * 16 + fr;
            float bb = bias[cc];
#pragma unroll
            for (int q = 0; q < 4; ++q)
                C[(r + q) * N + cc] = f2b(acc[i][j][q] + bb);
        }
    }
}

// ---------------- pooling: LN fused, chunked partial sums + atomics ----------------

__global__ void k_pool3(const unsigned short* __restrict__ z, const float2* __restrict__ st,
                        const float* __restrict__ g, const float* __restrict__ be,
                        const int* __restrict__ batch, float* __restrict__ pooled, int n) {
    int i0 = blockIdx.x * PCH;
    int iend = i0 + PCH; if (iend > n) iend = n;
    int t = threadIdx.x;  // 256 threads x 2 features
    float g0 = g[t * 2], g1 = g[t * 2 + 1];
    float e0 = be[t * 2], e1 = be[t * 2 + 1];
    float s0 = 0.f, s1 = 0.f;
    int cur = batch[i0];
    for (int i = i0; i < iend; ++i) {
        int gg = batch[i];
        if (gg != cur) {  // block-uniform branch
            atomicAdd(&pooled[(size_t)cur * 512 + t * 2], s0);
            atomicAdd(&pooled[(size_t)cur * 512 + t * 2 + 1], s1);
            s0 = s1 = 0.f;
            cur = gg;
        }
        float2 s2 = st[i];
        unsigned int u = *(const unsigned int*)(z + (size_t)i * 512 + t * 2);
        s0 += (b2f(u & 0xffffu) - s2.x) * s2.y * g0 + e0;
        s1 += (b2f(u >> 16) - s2.x) * s2.y * g1 + e1;
    }
    atomicAdd(&pooled[(size_t)cur * 512 + t * 2], s0);
    atomicAdd(&pooled[(size_t)cur * 512 + t * 2 + 1], s1);
}

// ---------------- final linear: out[G,128] = (pooled/cnt) @ Wf + bf ----------------

__global__ void k_final(const float* __restrict__ pooled, const int* __restrict__ batch,
                        const float* __restrict__ Wf, const float* __restrict__ bf,
                        float* __restrict__ out, int n) {
    int gph = blockIdx.x;
    int o = threadIdx.x;  // 128
    int lo = 0, hi = n;
    while (lo < hi) { int mid = (lo + hi) >> 1; if (batch[mid] < gph) lo = mid + 1; else hi = mid; }
    int start = lo;
    lo = start; hi = n;
    while (lo < hi) { int mid = (lo + hi) >> 1; if (batch[mid] < gph + 1) lo = mid + 1; else hi = mid; }
    int end = lo;
    float inv = 1.0f / fmaxf((float)(end - start), 1.0f);

    __shared__ float p[512];
    for (int k = threadIdx.x; k < 512; k += 128) p[k] = pooled[(size_t)gph * 512 + k] * inv;
    __syncthreads();
    float acc = bf[o];
#pragma unroll 8
    for (int k = 0; k < 512; ++k) acc += p[k] * Wf[(size_t)k * 128 + o];
    out[(size_t)gph * 128 + o] = acc;
}

// ---------------- host ----------------

static inline size_t align_up(size_t x) { return (x + 255) & ~(size_t)255; }

extern "C" void kernel_launch(void* const* d_in, const int* in_sizes, int n_in,
                              void* d_out, int out_size, void* d_ws, size_t ws_size,
                              hipStream_t stream) {
    const float* x     = (const float*)d_in[0];
    const int*   ei    = (const int*)d_in[1];
    const int*   batch = (const int*)d_in[2];
    const float* W1 = (const float*)d_in[4],  *b1 = (const float*)d_in[5];
    const float* g1 = (const float*)d_in[6],  *be1= (const float*)d_in[7];
    const float* W2 = (const float*)d_in[8],  *b2 = (const float*)d_in[9];
    const float* g2 = (const float*)d_in[10], *be2= (const float*)d_in[11];
    const float* W3 = (const float*)d_in[12], *b3 = (const float*)d_in[13];
    const float* g3 = (const float*)d_in[14], *be3= (const float*)d_in[15];
    const float* Wf = (const float*)d_in[16], *bf = (const float*)d_in[17];
    float* out = (float*)d_out;

    const int N = in_sizes[0] / 128;   // 50000
    const int E = in_sizes[1] / 2;     // 800000
    const int Mpad = ((N + BM - 1) / BM) * BM;   // 50048 (mult of 128 and 4)
    const int* src = ei;
    const int* dst = ei + E;

    char* ws = (char*)d_ws;
    size_t off = 0;
    auto take = [&](size_t bytes) { char* p = ws + off; off += align_up(bytes); return p; };

    unsigned short* zb      = (unsigned short*)take((size_t)Mpad * 512 * 2);  // pre-LN GEMM out
    unsigned short* aggb    = (unsigned short*)take((size_t)Mpad * 512 * 2);
    unsigned short* xb      = (unsigned short*)take((size_t)Mpad * 128 * 2);
    unsigned short* wt1     = (unsigned short*)take((size_t)256 * 128 * 2);
    unsigned short* wt2     = (unsigned short*)take((size_t)512 * 256 * 2);
    unsigned short* wt3     = (unsigned short*)take((size_t)512 * 512 * 2);
    float2*         st      = (float2*)take((size_t)Mpad * 8);
    float*          dinv    = (float*)take((size_t)N * 4);
    int*            rowstart= (int*)  take((size_t)(N + 1) * 4);
    int*            cnt     = (int*)  take((size_t)N * 4);
    int*            cursor  = (int*)  take((size_t)N * 4);
    int*            bsum    = (int*)  take((size_t)SCAN_B * 4);
    int2*           csr     = (int2*) take((size_t)E * 8);
    float*          pooled  = (float*)take((size_t)GRAPHS * 512 * 4);

    const int nb = (N + SCAN_B - 1) / SCAN_B;
    const int NC4 = Mpad / 4;   // node chunks for agg/stats grids

    // CSR build
    hipMemsetAsync(cnt, 0, (size_t)N * 4, stream);
    k_count<<<(E + 255) / 256, 256, 0, stream>>>(dst, cnt, E);
    k_scan1<<<nb, SCAN_B, 0, stream>>>(cnt, rowstart, bsum, N);
    k_scan2<<<1, SCAN_B, 0, stream>>>(bsum, nb);
    k_scan3<<<nb, SCAN_B, 0, stream>>>(rowstart, bsum, cnt, dinv, cursor, N, E);
    k_scatter_csr<<<(E + 255) / 256, 256, 0, stream>>>(src, dst, dinv, rowstart, cursor, csr, E);

    // weights -> bf16 transposed
    k_wt<<<(128 * 256 + 255) / 256, 256, 0, stream>>>(W1, wt1, 128, 256);
    k_wt<<<(256 * 512 + 255) / 256, 256, 0, stream>>>(W2, wt2, 256, 512);
    k_wt<<<(512 * 512 + 255) / 256, 256, 0, stream>>>(W3, wt3, 512, 512);

    // x -> bf16 (padded)
    k_x2b<<<(Mpad * 32 + 255) / 256, 256, 0, stream>>>(x, xb, N, Mpad);

    // Layer 1: agg(x) -> GEMM(K=128,N=256)+bias -> z1 ; stats1
    k_aggw<128, false, false><<<2 * NC4, 256, 0, stream>>>(
        xb, aggb, rowstart, csr, dinv, nullptr, nullptr, nullptr, N, Mpad);
    { dim3 grid(Mpad / BM, 256 / BN);
      k_gemm_bf16<<<grid, 256, 0, stream>>>(aggb, wt1, b1, zb, 128, 256); }
    k_stats<256><<<NC4, 256, 0, stream>>>(zb, st, Mpad);

    // Layer 2: agg(LN+lrelu(z1)) -> GEMM(K=256,N=512)+bias -> z2 ; stats2
    k_aggw<256, true, true><<<4 * NC4, 256, 0, stream>>>(
        zb, aggb, rowstart, csr, dinv, st, g1, be1, N, Mpad);
    { dim3 grid(Mpad / BM, 512 / BN);
      k_gemm_bf16<<<grid, 256, 0, stream>>>(aggb, wt2, b2, zb, 256, 512); }
    k_stats<512><<<NC4, 256, 0, stream>>>(zb, st, Mpad);

    // Layer 3: agg(LN+lrelu(z2)) -> GEMM(K=512,N=512)+bias -> z3 ; stats3
    k_aggw<512, true, true><<<8 * NC4, 256, 0, stream>>>(
        zb, aggb, rowstart, csr, dinv, st, g2, be2, N, Mpad);
    { dim3 grid(Mpad / BM, 512 / BN);
      k_gemm_bf16<<<grid, 256, 0, stream>>>(aggb, wt3, b3, zb, 512, 512); }
    k_stats<512><<<NC4, 256, 0, stream>>>(zb, st, Mpad);

    // pool (LN fused) + final
    hipMemsetAsync(pooled, 0, (size_t)GRAPHS * 512 * 4, stream);
    k_pool3<<<(N + PCH - 1) / PCH, 256, 0, stream>>>(zb, st, g3, be3, batch, pooled, N);
    k_final<<<GRAPHS, 128, 0, stream>>>(pooled, batch, Wf, bf, out, N);
}